// Round 1
// baseline (255.255 us; speedup 1.0000x reference)
//
#include <hip/hip_runtime.h>
#include <cstdint>

typedef unsigned short u16;
typedef __attribute__((ext_vector_type(8))) short short8;
typedef __attribute__((ext_vector_type(16))) float f32x16;

// RNE float -> bf16 (bit pattern)
__device__ __forceinline__ u16 f2bf(float f) {
  uint32_t u = __float_as_uint(f);
  u += 0x7FFFu + ((u >> 16) & 1u);
  return (u16)(u >> 16);
}

// async global->LDS, 16B per lane. LDS dest must be wave-uniform base + lane*16.
__device__ __forceinline__ void async_ld16(u16* lds, const u16* g) {
  __builtin_amdgcn_global_load_lds((const __attribute__((address_space(1))) uint32_t*)g,
                                   (__attribute__((address_space(3))) uint32_t*)lds,
                                   16, 0, 0);
}

// phase fences (rule #18: sched_barrier(0) after inline-asm waitcnt, else MFMA hoists past it)
__device__ __forceinline__ void lgkm0_fence() {
  asm volatile("s_waitcnt lgkmcnt(0)" ::: "memory");
  __builtin_amdgcn_sched_barrier(0);
}
__device__ __forceinline__ void vmw6_fence() {
  asm volatile("s_waitcnt vmcnt(6)" ::: "memory");
  __builtin_amdgcn_sched_barrier(0);
}
__device__ __forceinline__ void vmw0_fence() {
  asm volatile("s_waitcnt vmcnt(0)" ::: "memory");
  __builtin_amdgcn_sched_barrier(0);
}

#define MFMA32 __builtin_amdgcn_mfma_f32_32x32x16_bf16

// ---------------------------------------------------------------------------
// g8: 256x256xBK64 8-wave 4-phase/K-tile GEMM core (T2+T3+T4+T5 stack).
//   - 512 threads = 8 waves, 2x4 wave grid; per-wave output 128x64
//     (4 m-frags x 2 n-frags of 32x32, acc = 8 x f32x16 = 128 VGPR).
//   - LDS 128 KiB: ls[buf][A/B][256*64] bf16, K-major rows of 64 elems
//     (8 x 16B granules). XOR swizzle: granule position = g ^ (row&7);
//     global_load_lds writes linearly, so the SOURCE granule is pre-swizzled
//     (both-sides-or-neither rule, m201 pattern).
//   - Per K-tile (BK=64), 4 phases: {ds_read subtile || stage half-tile ->
//     s_barrier -> lgkmcnt(0) -> setprio(1) -> 8 MFMA -> setprio(0) ->
//     s_barrier}. Stage schedule: ph0 -> (t+1).A-half1 (into idle buf);
//     ph2 -> (t+2).B-half0 (B halves' last reader is ph1, barrier-separated);
//     ph3 -> (t+2).{B-half1, A-half0} (A halves' last reader is ph2).
//     Counted vmcnt(6) ONCE per K-tile (= 3 half-tiles x 2 loads in flight);
//     never vmcnt(0) in steady state.
//   - lda = ldb = 1024 for every role here (hard-coded).
// ROLE 0: grid 384. b<256: Q/K projection (mat=b>>7). b>=256: V^T directly
//         (A=Wtv rows d, B=Xbf rows t), ldc=8192.
// ROLE 1: grid 144. Causal scores, lower-triangle 256-tiles (36/batch x 4).
//         Epilogue: exp(s/32), causal mask, P bf16, per-64col-chunk fp32 row
//         partial sums -> lpart (chunk = col/64, same layout PV expects).
// ---------------------------------------------------------------------------
template <int ROLE>
__global__ __launch_bounds__(512, 2) void g8(
    const u16* __restrict__ Xbf, const u16* __restrict__ Wt,
    u16* __restrict__ QK, u16* __restrict__ VtAll,
    u16* __restrict__ P, float* __restrict__ lpart)
{
  const int b = blockIdx.x;
  const int tid = threadIdx.x;
  const int lane = tid & 63;
  const int wave = tid >> 6;
  const int wr2 = wave >> 2;   // 0..1: 128-row half of the 256-row tile
  const int wc2 = wave & 3;    // 0..3: 64-col slice
  const int m32 = lane & 31;
  const int hh = lane >> 5;

  __shared__ __align__(16) u16 ls[2][2][16384];  // [buf][A=0/B=1][256*64]

  // ---- per-role operand decode ----
  const u16 *A, *B;
  u16* C = nullptr;
  long ldc = 1024;
  int m0, n0, zb = 0, nt = 0;

  if constexpr (ROLE == 0) {
    if (b < 256) {                       // Q (mat 0), K (mat 1)
      const int mat = b >> 7, v = b & 127;
      m0 = (v >> 2) * 256;               // 32 M-tiles
      n0 = (v & 3) * 256;                // 4 N-tiles
      A = Xbf;
      B = Wt + (long)mat * 1024 * 1024;
      C = QK + (long)mat * 8192 * 1024;
      ldc = 1024;
    } else {                             // V^T: Vt[d][t] = Wtv x Xbf^T
      const int v = b - 256;
      m0 = (v >> 5) * 256;               // 4 d-tiles
      n0 = (v & 31) * 256;               // 32 t-tiles (global 8192)
      A = Wt + 2L * 1024 * 1024;
      B = Xbf;
      C = VtAll;
      ldc = 8192;
    }
  } else {                               // causal scores
    zb = b / 36;
    const int w = b - zb * 36;
    int mt = 0;
    while ((mt + 1) * (mt + 2) / 2 <= w) ++mt;   // triangle decode, nt <= mt
    nt = w - mt * (mt + 1) / 2;
    m0 = mt * 256;
    n0 = nt * 256;
    A = QK + (long)zb * 2048 * 1024;                   // Q rows (k-major)
    B = QK + 8192L * 1024 + (long)zb * 2048 * 1024;    // K rows (k-major)
  }

  // ---- staging source pointers (pre-swizzled granule: src g = pos ^ (row&7)) ----
  // granule c = tid + g*512: row = c>>3, pos = c&7; (row&7) invariant across g.
  const int sr = tid >> 3, sg = tid & 7;
  const u16* pAst = A + (long)(m0 + sr) * 1024 + ((sg ^ (sr & 7)) * 8);
  const u16* pBst = B + (long)(n0 + sr) * 1024 + ((sg ^ (sr & 7)) * 8);

#define STG_A(bf, h, t_) do { \
    u16* _d = &ls[bf][0][(h) * 8192] + tid * 8; \
    const u16* _s = pAst + (long)(h) * 131072 + (long)(t_) * 64; \
    async_ld16(_d, _s); async_ld16(_d + 4096, _s + 65536); } while (0)
#define STG_B(bf, h, t_) do { \
    u16* _d = &ls[bf][1][(h) * 8192] + tid * 8; \
    const u16* _s = pBst + (long)(h) * 131072 + (long)(t_) * 64; \
    async_ld16(_d, _s); async_ld16(_d + 4096, _s + 65536); } while (0)

  // ---- loop-invariant ds_read offsets (u16 units); frag (i,j) adds i*2048 / j*2048 ----
  int offAk[4], offBk[4];
#pragma unroll
  for (int ks = 0; ks < 4; ++ks) {
    const int kq = ((ks << 1) | hh) ^ (m32 & 7);   // read-side swizzle = write-side
    offAk[ks] = (wr2 * 128 + m32) * 64 + kq * 8;
    offBk[ks] = (wc2 * 64 + m32) * 64 + kq * 8;
  }

  f32x16 acc[4][2];
#pragma unroll
  for (int i = 0; i < 4; ++i)
#pragma unroll
    for (int j = 0; j < 2; ++j)
#pragma unroll
      for (int r = 0; r < 16; ++r) acc[i][j][r] = 0.f;

  // ---- prologue: tile0 complete (8 loads) + tile1 {B0,B1,A0} (6 loads) ----
  STG_A(0, 0, 0); STG_A(0, 1, 0); STG_B(0, 0, 0); STG_B(0, 1, 0);
  STG_B(1, 0, 1); STG_B(1, 1, 1); STG_A(1, 0, 1);
  vmw6_fence();                      // tile0's 8 landed; tile1's 6 in flight
  __builtin_amdgcn_s_barrier();

  short8 A0[4], A1[4], A2[4], A3[4], B0r[4], B1r[4];

#pragma unroll 1
  for (int t = 0; t < 16; ++t) {     // NT = 1024/64 = 16, all roles
    const u16* la = ls[t & 1][0];
    const u16* lb = ls[t & 1][1];

    // ---- phase 0: read A0,A1,B0 (12) | stage (t+1).A1 | mfma (m0,m1)xn0
#pragma unroll
    for (int ks = 0; ks < 4; ++ks) {
      A0[ks]  = *(const short8*)&la[offAk[ks]];
      A1[ks]  = *(const short8*)&la[offAk[ks] + 2048];
      B0r[ks] = *(const short8*)&lb[offBk[ks]];
    }
    if (t < 15) STG_A((t + 1) & 1, 1, t + 1);
    __builtin_amdgcn_s_barrier();
    lgkm0_fence();
    __builtin_amdgcn_s_setprio(1);
#pragma unroll
    for (int ks = 0; ks < 4; ++ks) {
      acc[0][0] = MFMA32(A0[ks], B0r[ks], acc[0][0], 0, 0, 0);
      acc[1][0] = MFMA32(A1[ks], B0r[ks], acc[1][0], 0, 0, 0);
    }
    __builtin_amdgcn_s_setprio(0);
    __builtin_amdgcn_s_barrier();

    // ---- phase 1: read B1 (4) | no stage | mfma (m0,m1)xn1
#pragma unroll
    for (int ks = 0; ks < 4; ++ks)
      B1r[ks] = *(const short8*)&lb[offBk[ks] + 2048];
    __builtin_amdgcn_s_barrier();
    lgkm0_fence();
    __builtin_amdgcn_s_setprio(1);
#pragma unroll
    for (int ks = 0; ks < 4; ++ks) {
      acc[0][1] = MFMA32(A0[ks], B1r[ks], acc[0][1], 0, 0, 0);
      acc[1][1] = MFMA32(A1[ks], B1r[ks], acc[1][1], 0, 0, 0);
    }
    __builtin_amdgcn_s_setprio(0);
    __builtin_amdgcn_s_barrier();

    // ---- phase 2: read A2,A3 (8) | stage (t+2).B0 | mfma (m2,m3)xn0
#pragma unroll
    for (int ks = 0; ks < 4; ++ks) {
      A2[ks] = *(const short8*)&la[offAk[ks] + 4096];
      A3[ks] = *(const short8*)&la[offAk[ks] + 6144];
    }
    if (t < 14) STG_B(t & 1, 0, t + 2);
    __builtin_amdgcn_s_barrier();
    lgkm0_fence();
    __builtin_amdgcn_s_setprio(1);
#pragma unroll
    for (int ks = 0; ks < 4; ++ks) {
      acc[2][0] = MFMA32(A2[ks], B0r[ks], acc[2][0], 0, 0, 0);
      acc[3][0] = MFMA32(A3[ks], B0r[ks], acc[3][0], 0, 0, 0);
    }
    __builtin_amdgcn_s_setprio(0);
    __builtin_amdgcn_s_barrier();

    // ---- phase 3: no reads | stage (t+2).{B1,A0} | mfma (m2,m3)xn1 | vmcnt(6)
    if (t < 14) { STG_B(t & 1, 1, t + 2); STG_A(t & 1, 0, t + 2); }
    __builtin_amdgcn_s_barrier();
    __builtin_amdgcn_s_setprio(1);
#pragma unroll
    for (int ks = 0; ks < 4; ++ks) {
      acc[2][1] = MFMA32(A2[ks], B1r[ks], acc[2][1], 0, 0, 0);
      acc[3][1] = MFMA32(A3[ks], B1r[ks], acc[3][1], 0, 0, 0);
    }
    __builtin_amdgcn_s_setprio(0);
    if (t < 14) vmw6_fence(); else vmw0_fence();
    __builtin_amdgcn_s_barrier();
  }
#undef STG_A
#undef STG_B

  // C/D layout 32x32 (m74/m101): col = lane&31, row = (reg&3)+8*(reg>>2)+4*(lane>>5)
  const int ec = lane & 31;
  const int rb = hh * 4;

  if constexpr (ROLE == 0) {
#pragma unroll
    for (int i = 0; i < 4; ++i) {
      const int rbase = m0 + wr2 * 128 + i * 32 + rb;
#pragma unroll
      for (int j = 0; j < 2; ++j) {
        const int col = n0 + wc2 * 64 + j * 32 + ec;
#pragma unroll
        for (int r = 0; r < 16; ++r) {
          const int row = rbase + (r & 3) + 8 * (r >> 2);
          C[(long)row * ldc + col] = f2bf(acc[i][j][r]);
        }
      }
    }
  } else {
    u16* Cp = P + (long)zb * 2048 * 2048;
    float* lp = lpart + (long)zb * 32 * 2048 + (long)(nt * 4 + wc2) * 2048;
#pragma unroll
    for (int i = 0; i < 4; ++i) {
      const int rbl = wr2 * 128 + i * 32 + rb;   // local row base within tile
      float rsum[16];
#pragma unroll
      for (int r = 0; r < 16; ++r) rsum[r] = 0.f;
#pragma unroll
      for (int j = 0; j < 2; ++j) {
        const int col = n0 + wc2 * 64 + j * 32 + ec;
#pragma unroll
        for (int r = 0; r < 16; ++r) {
          const int row = m0 + rbl + (r & 3) + 8 * (r >> 2);
          float pv = __expf(acc[i][j][r] * 0.03125f);
          if (col > row) pv = 0.f;
          Cp[(long)row * 2048 + col] = f2bf(pv);
          rsum[r] += pv;
        }
      }
#pragma unroll
      for (int r = 0; r < 16; ++r) {
        float s = rsum[r];
#pragma unroll
        for (int off = 1; off < 32; off <<= 1) s += __shfl_xor(s, off, 64);
        if ((lane & 31) == 0)
          lp[m0 + rbl + (r & 3) + 8 * (r >> 2)] = s;
      }
    }
  }
}

// ---------------------------------------------------------------------------
// Legacy 128x128xBK32 core — kept ONLY for ROLE 2 (PV): ragged K (clipped at
// the causal diagonal) needs the 4-blocks/CU granularity; epilogue builds
// 1/l per row from lpart chunks and writes fp32 out.
// ---------------------------------------------------------------------------
template <int ROLE>
__global__ __launch_bounds__(256) void gk(
    const u16* __restrict__ Xbf, const u16* __restrict__ Wt,
    u16* __restrict__ QK, u16* __restrict__ VtAll,
    u16* __restrict__ P, float* __restrict__ lpart,
    float* __restrict__ out)
{
  const int b = blockIdx.x;
  const int tid = threadIdx.x;
  const int lane = tid & 63;
  const int wave = tid >> 6;
  const int wr = (wave >> 1) * 64;
  const int wc = (wave & 1) * 64;

  __shared__ __align__(16) u16 ls[4][4096];  // A0,A1,B0,B1 (128x32 each)
  __shared__ float l_s[128];                 // ROLE 2 only

  const int c0 = tid, c1 = tid + 256;
  const int r0 = c0 >> 2, q0 = ((c0 & 3) ^ ((c0 >> 3) & 3)) * 8;
  const int r1 = c1 >> 2, q1 = ((c1 & 3) ^ ((c1 >> 3) & 3)) * 8;

  const int m32 = lane & 31;
  const int hh = lane >> 5;
  const int rsw = (m32 >> 1) & 3;
  int offA[2][2], offB[2][2];
#pragma unroll
  for (int i = 0; i < 2; ++i)
#pragma unroll
    for (int ks = 0; ks < 2; ++ks) {
      const int kq = ((ks << 1) | hh) ^ rsw;
      offA[i][ks] = (wr + i * 32 + m32) * 32 + kq * 8;
      offB[i][ks] = (wc + i * 32 + m32) * 32 + kq * 8;
    }

  // ---- ROLE 2 operand decode (PV) ----
  const u16 *A, *B;
  int lda, ldb, kmax, m0, n0, mb, nb, zb = 0;
  const int u = b & 7, idx = b >> 3;    // idx in [0,16)
  zb = blockIdx.y;
  if (idx < 8) { mb = 15 - u; nb = idx; }      // big work first
  else         { mb = u;      nb = idx - 8; }
  A = P + (long)zb * 2048 * 2048; lda = 2048;
  B = VtAll + (long)zb * 2048; ldb = 8192;     // Vt rows d, batch k-slice
  kmax = (mb + 1) * 128;
  m0 = mb * 128;
  n0 = nb * 128;

  const u16* pA0 = A + (long)(m0 + r0) * lda + q0;
  const u16* pA1 = A + (long)(m0 + r1) * lda + q1;
  const u16* pB0 = B + (long)(n0 + r0) * ldb + q0;
  const u16* pB1 = B + (long)(n0 + r1) * ldb + q1;

  f32x16 acc[2][2];
#pragma unroll
  for (int i = 0; i < 2; ++i)
#pragma unroll
    for (int j = 0; j < 2; ++j)
#pragma unroll
      for (int r = 0; r < 16; ++r) acc[i][j][r] = 0.f;

  async_ld16(&ls[0][c0 * 8], pA0);
  async_ld16(&ls[0][c1 * 8], pA1);
  async_ld16(&ls[2][c0 * 8], pB0);
  async_ld16(&ls[2][c1 * 8], pB1);
  pA0 += 32; pA1 += 32; pB0 += 32; pB1 += 32;

  int p = 0;
  for (int k0 = 0; k0 < kmax; k0 += 32) {
    __syncthreads();
    if (k0 + 32 < kmax) {
      u16* la = ls[p ^ 1];
      u16* lb = ls[2 + (p ^ 1)];
      async_ld16(&la[c0 * 8], pA0);
      async_ld16(&la[c1 * 8], pA1);
      async_ld16(&lb[c0 * 8], pB0);
      async_ld16(&lb[c1 * 8], pB1);
      pA0 += 32; pA1 += 32; pB0 += 32; pB1 += 32;
    }

    const u16* la = ls[p];
    const u16* lb = ls[2 + p];
#pragma unroll
    for (int ks = 0; ks < 2; ++ks) {
      const short8 a0 = *(const short8*)&la[offA[0][ks]];
      const short8 a1 = *(const short8*)&la[offA[1][ks]];
      const short8 b0 = *(const short8*)&lb[offB[0][ks]];
      const short8 b1 = *(const short8*)&lb[offB[1][ks]];
      acc[0][0] = MFMA32(a0, b0, acc[0][0], 0, 0, 0);
      acc[0][1] = MFMA32(a0, b1, acc[0][1], 0, 0, 0);
      acc[1][0] = MFMA32(a1, b0, acc[1][0], 0, 0, 0);
      acc[1][1] = MFMA32(a1, b1, acc[1][1], 0, 0, 0);
    }
    p ^= 1;
  }

  const int ec = lane & 31;
  const int rb = (lane >> 5) * 4;

  // PV epilogue: build 1/l per row from lpart chunks, then multiply
  __syncthreads();  // staging LDS dead
  if (tid < 128) {
    const float* lp = lpart + (long)zb * 32 * 2048 + m0 + tid;
    float s0 = 0.f, s1 = 0.f;
    const int nch = 2 * (mb + 1);
    for (int c = 0; c < nch; c += 2) {
      s0 += lp[(long)c * 2048];
      s1 += lp[(long)(c + 1) * 2048];
    }
    l_s[tid] = 1.f / (s0 + s1);
  }
  __syncthreads();
  float* Cf = out + (long)zb * 2048 * 1024;
#pragma unroll
  for (int i = 0; i < 2; ++i) {
    const int rbl = wr + i * 32 + rb;
#pragma unroll
    for (int j = 0; j < 2; ++j) {
      const int col = n0 + wc + j * 32 + ec;
#pragma unroll
      for (int r = 0; r < 16; ++r) {
        const int rl = rbl + (r & 3) + 8 * (r >> 2);
        Cf[(long)(m0 + rl) * 1024 + col] = acc[i][j][r] * l_s[rl];
      }
    }
  }
}

// ---------------------------------------------------------------------------
// Fused casts: blocks [0,8192): X fp32->bf16 (1024 elems each);
// blocks [8192,11264): W_{q,k,v}[k][n] fp32 -> Wt[n][k] bf16 (32x32 tiles).
// ---------------------------------------------------------------------------
__global__ __launch_bounds__(256) void cast_fused(
    const float* __restrict__ x, const float* __restrict__ w0,
    const float* __restrict__ w1, const float* __restrict__ w2,
    u16* __restrict__ Xbf, u16* __restrict__ Wt)
{
  const int b = blockIdx.x;
  if (b < 8192) {
    const long i = ((long)b * 256 + threadIdx.x) * 4;
    const float4 v = *(const float4*)(x + i);
    ushort4 o;
    o.x = f2bf(v.x); o.y = f2bf(v.y); o.z = f2bf(v.z); o.w = f2bf(v.w);
    *(ushort4*)(Xbf + i) = o;
  } else {
    const int bb = b - 8192;               // [0,3072)
    const int z = bb >> 10, rem = bb & 1023;
    const float* W = (z == 0) ? w0 : (z == 1) ? w1 : w2;
    u16* o = Wt + (long)z * 1024 * 1024;
    __shared__ float t[32][33];
    const int n0 = (rem & 31) * 32, k0 = (rem >> 5) * 32;
    const int tx = threadIdx.x & 31, ty = threadIdx.x >> 5;
    for (int r = ty; r < 32; r += 8) t[r][tx] = W[(long)(k0 + r) * 1024 + n0 + tx];
    __syncthreads();
    for (int r = ty; r < 32; r += 8) o[(long)(n0 + r) * 1024 + k0 + tx] = f2bf(t[tx][r]);
  }
}

// ---------------------------------------------------------------------------
extern "C" void kernel_launch(void* const* d_in, const int* in_sizes, int n_in,
                              void* d_out, int out_size, void* d_ws, size_t ws_size,
                              hipStream_t stream) {
  const float* X  = (const float*)d_in[0];
  const float* Wq = (const float*)d_in[1];
  const float* Wk = (const float*)d_in[2];
  const float* Wv = (const float*)d_in[3];
  float* out = (float*)d_out;

  // workspace (~103 MiB)
  u16* Xbf   = (u16*)d_ws;                   // 8192*1024            16 MB
  u16* Wt    = Xbf + 8192L * 1024;           // 3*1024*1024           6 MB
  u16* QK    = Wt + 3L * 1024 * 1024;        // 2*8192*1024          32 MB
  u16* VtAll = QK + 2L * 8192 * 1024;        // 1024*8192            16 MB
  u16* P     = VtAll + 1024L * 8192;         // 4*2048*2048          32 MB
  float* lpart = (float*)(P + 4L * 2048 * 2048);  // 4*32*2048        1 MB

  cast_fused<<<8192 + 3072, 256, 0, stream>>>(X, Wq, Wk, Wv, Xbf, Wt);

  // Q,K projections (256 blocks) + V^T projection (128 blocks): 256^2 8-phase core
  g8<0><<<384, 512, 0, stream>>>(Xbf, Wt, QK, VtAll, P, lpart);

  // causal scores: 36 lower-triangle 256-tiles x 4 batches
  g8<1><<<144, 512, 0, stream>>>(Xbf, Wt, QK, VtAll, P, lpart);

  // PV: 512 blocks, big-mb-first, epilogue normalizes via lpart
  gk<2><<<dim3(128, 4), 256, 0, stream>>>(Xbf, Wt, QK, VtAll, P, lpart, out);
}